// Round 4
// baseline (290.134 us; speedup 1.0000x reference)
//
#include <hip/hip_runtime.h>
#include <hip/hip_fp16.h>

// GraphSAGE (mean agg), 3 layers + linear head, fp32 accum, fp16 transport.
// R15: gather restructured for VMEM-instruction/segment throughput (last
// surviving theory after bytes/streams/latency/line-count all nulled):
//  - 6 lanes x uint4 (16B) per neighbor row, no parity split: one wave-inst
//    moves 768B payload / 16 lines vs 512B / ~20 lines before (2.2x fewer
//    gather instructions per byte, -40% divergent segments per byte).
//  - node math relaid to 8-col slices (j<6 active): GEMM shuffle loop
//    jo(0..5) x r(0..7) static-indexed; weights read as uint4 from LDS
//    (16B aligned, conflict-free); uint4 stores.
//  - K0 (fill atomic floor ~46us, channel-throughput) unchanged & shelved.

constexpr int HID = 48;
constexpr int MAXDEG = 64;
constexpr int RSTRIDE = 64;    // halfs per padded feature row (128 B)
constexpr int GNB = 64;        // nodes per K0 proj block

__device__ __forceinline__ unsigned pack_h2(float a, float b) {
    __half2 h = __floats2half2_rn(a, b);
    return *reinterpret_cast<unsigned*>(&h);
}
__device__ __forceinline__ void acc_u2(float* g, uint2 u) {
    __half2 h0 = *reinterpret_cast<__half2*>(&u.x);
    __half2 h1 = *reinterpret_cast<__half2*>(&u.y);
    float2 f0 = __half22float2(h0), f1 = __half22float2(h1);
    g[0] += f0.x; g[1] += f0.y; g[2] += f1.x; g[3] += f1.y;
}
__device__ __forceinline__ void acc_u4(float* g, uint4 u) {
    acc_u2(g + 0, make_uint2(u.x, u.y));
    acc_u2(g + 4, make_uint2(u.z, u.w));
}
__device__ __forceinline__ void unpack_u2(float* v, uint2 u) {
    __half2 h0 = *reinterpret_cast<__half2*>(&u.x);
    __half2 h1 = *reinterpret_cast<__half2*>(&u.y);
    float2 f0 = __half22float2(h0), f1 = __half22float2(h1);
    v[0] = f0.x; v[1] = f0.y; v[2] = f1.x; v[3] = f1.y;
}
__device__ __forceinline__ void unpack_u4(float* v, uint4 u) {
    unpack_u2(v + 0, make_uint2(u.x, u.y));
    unpack_u2(v + 4, make_uint2(u.z, u.w));
}

// Wide gather: this thread accumulates cols [coff, coff+8) (halfs) of all
// deg neighbor rows. Entries [0,16) prefetched in pw (out-of-degree ->
// zrow = all-zero row); [16, deg) via residual loop. One uint4 per row.
__device__ __forceinline__ void gather_w(const __half* __restrict__ p,
                                         const unsigned short* __restrict__ bkt,
                                         const uint4 (&pw)[2], int deg,
                                         int coff, int zrow, float* g) {
    float ga[8], gb[8];
#pragma unroll
    for (int c = 0; c < 8; ++c) { ga[c] = 0.0f; gb[c] = 0.0f; }
#pragma unroll
    for (int b = 0; b < 2; ++b) {
        const int k0 = 8 * b;
        const unsigned w0 = pw[b].x, w1 = pw[b].y, w2 = pw[b].z, w3 = pw[b].w;
        int i0 = (k0 + 0 < deg) ? (int)(w0 & 0xffffu) : zrow;
        int i1 = (k0 + 1 < deg) ? (int)(w0 >> 16) : zrow;
        int i2 = (k0 + 2 < deg) ? (int)(w1 & 0xffffu) : zrow;
        int i3 = (k0 + 3 < deg) ? (int)(w1 >> 16) : zrow;
        int i4 = (k0 + 4 < deg) ? (int)(w2 & 0xffffu) : zrow;
        int i5 = (k0 + 5 < deg) ? (int)(w2 >> 16) : zrow;
        int i6 = (k0 + 6 < deg) ? (int)(w3 & 0xffffu) : zrow;
        int i7 = (k0 + 7 < deg) ? (int)(w3 >> 16) : zrow;
        uint4 a0 = *reinterpret_cast<const uint4*>(p + (size_t)i0 * RSTRIDE + coff);
        uint4 a1 = *reinterpret_cast<const uint4*>(p + (size_t)i1 * RSTRIDE + coff);
        uint4 a2 = *reinterpret_cast<const uint4*>(p + (size_t)i2 * RSTRIDE + coff);
        uint4 a3 = *reinterpret_cast<const uint4*>(p + (size_t)i3 * RSTRIDE + coff);
        uint4 a4 = *reinterpret_cast<const uint4*>(p + (size_t)i4 * RSTRIDE + coff);
        uint4 a5 = *reinterpret_cast<const uint4*>(p + (size_t)i5 * RSTRIDE + coff);
        uint4 a6 = *reinterpret_cast<const uint4*>(p + (size_t)i6 * RSTRIDE + coff);
        uint4 a7 = *reinterpret_cast<const uint4*>(p + (size_t)i7 * RSTRIDE + coff);
        acc_u4(ga, a0); acc_u4(gb, a1); acc_u4(ga, a2); acc_u4(gb, a3);
        acc_u4(ga, a4); acc_u4(gb, a5); acc_u4(ga, a6); acc_u4(gb, a7);
    }
    int i = 16;
    for (; i + 3 < deg; i += 4) {
        int s0 = bkt[i], s1 = bkt[i + 1], s2 = bkt[i + 2], s3 = bkt[i + 3];
        uint4 a0 = *reinterpret_cast<const uint4*>(p + (size_t)s0 * RSTRIDE + coff);
        uint4 a1 = *reinterpret_cast<const uint4*>(p + (size_t)s1 * RSTRIDE + coff);
        uint4 a2 = *reinterpret_cast<const uint4*>(p + (size_t)s2 * RSTRIDE + coff);
        uint4 a3 = *reinterpret_cast<const uint4*>(p + (size_t)s3 * RSTRIDE + coff);
        acc_u4(ga, a0); acc_u4(gb, a1); acc_u4(ga, a2); acc_u4(gb, a3);
    }
    for (; i < deg; ++i) {
        uint4 a0 = *reinterpret_cast<const uint4*>(p + (size_t)bkt[i] * RSTRIDE + coff);
        acc_u4(ga, a0);
    }
#pragma unroll
    for (int c = 0; c < 8; ++c) g[c] = ga[c] + gb[c];
}

// ---- K0: blocks [0,gemm_blocks) compute p0 = fp16(X @ Wn); rest fill buckets ----
__global__ __launch_bounds__(128) void fill_proj_k(
    const float* __restrict__ X, const float* __restrict__ Wn,
    __half* __restrict__ p_out, int n_nodes,
    const int* __restrict__ src, const int* __restrict__ dst,
    int* __restrict__ cnt, unsigned short* __restrict__ buckets,
    int n_edges, int gemm_blocks, int cstride) {
    __shared__ float wlds[96 * HID];
    const int t = threadIdx.x;

    if ((int)blockIdx.x >= gemm_blocks) {
        // 4 edges/thread: 4 independent atomics in flight per thread
        int base = (blockIdx.x - gemm_blocks) * 512 + t;
#pragma unroll
        for (int u = 0; u < 4; ++u) {
            int eidx = base + u * 128;
            if (eidx < n_edges) {
                int d = dst[eidx];
                int s = src[eidx];
                int pos = atomicAdd(&cnt[(size_t)d * cstride], 1);
                if (pos < MAXDEG) buckets[(size_t)d * MAXDEG + pos] = (unsigned short)s;
            }
        }
        return;
    }

    // zero row at index n_nodes for the gather zero-redirect trick
    if (blockIdx.x == 0 && t < 32)
        reinterpret_cast<unsigned*>(p_out + (size_t)n_nodes * RSTRIDE)[t] = 0u;

    const int q = t & 3;
    const int m = t >> 2;
    const int jb = q * 12;
    const int n0 = blockIdx.x * GNB + 2 * m;
    const int n1 = n0 + 1;
    const bool v0 = n0 < n_nodes, v1 = n1 < n_nodes;
    const int cn0 = v0 ? n0 : 0, cn1 = v1 ? n1 : 0;
    const float4* xr0 = reinterpret_cast<const float4*>(X + (size_t)cn0 * 96);
    const float4* xr1 = reinterpret_cast<const float4*>(X + (size_t)cn1 * 96);

    for (int i = t; i < 96 * HID; i += 128) wlds[i] = Wn[i];
    __syncthreads();

    float pa[12], pb[12];
#pragma unroll
    for (int j = 0; j < 12; ++j) { pa[j] = 0.0f; pb[j] = 0.0f; }
#pragma unroll 4
    for (int k4 = 0; k4 < 24; ++k4) {
        float4 xa = xr0[k4];
        float4 xb = xr1[k4];
#pragma unroll
        for (int c = 0; c < 4; ++c) {
            float x0 = (c == 0) ? xa.x : (c == 1) ? xa.y : (c == 2) ? xa.z : xa.w;
            float x1 = (c == 0) ? xb.x : (c == 1) ? xb.y : (c == 2) ? xb.z : xb.w;
            const float4* wr =
                reinterpret_cast<const float4*>(&wlds[(k4 * 4 + c) * HID + jb]);
#pragma unroll
            for (int j4 = 0; j4 < 3; ++j4) {
                float4 wv = wr[j4];
                pa[j4 * 4 + 0] = fmaf(x0, wv.x, pa[j4 * 4 + 0]);
                pa[j4 * 4 + 1] = fmaf(x0, wv.y, pa[j4 * 4 + 1]);
                pa[j4 * 4 + 2] = fmaf(x0, wv.z, pa[j4 * 4 + 2]);
                pa[j4 * 4 + 3] = fmaf(x0, wv.w, pa[j4 * 4 + 3]);
                pb[j4 * 4 + 0] = fmaf(x1, wv.x, pb[j4 * 4 + 0]);
                pb[j4 * 4 + 1] = fmaf(x1, wv.y, pb[j4 * 4 + 1]);
                pb[j4 * 4 + 2] = fmaf(x1, wv.z, pb[j4 * 4 + 2]);
                pb[j4 * 4 + 3] = fmaf(x1, wv.w, pb[j4 * 4 + 3]);
            }
        }
    }
    if (v0) {
        uint2* po = reinterpret_cast<uint2*>(p_out + (size_t)n0 * RSTRIDE + jb);
        po[0] = make_uint2(pack_h2(pa[0], pa[1]), pack_h2(pa[2], pa[3]));
        po[1] = make_uint2(pack_h2(pa[4], pa[5]), pack_h2(pa[6], pa[7]));
        po[2] = make_uint2(pack_h2(pa[8], pa[9]), pack_h2(pa[10], pa[11]));
    }
    if (v1) {
        uint2* po = reinterpret_cast<uint2*>(p_out + (size_t)n1 * RSTRIDE + jb);
        po[0] = make_uint2(pack_h2(pb[0], pb[1]), pack_h2(pb[2], pb[3]));
        po[1] = make_uint2(pack_h2(pb[4], pb[5]), pack_h2(pb[6], pb[7]));
        po[2] = make_uint2(pack_h2(pb[8], pb[9]), pack_h2(pb[10], pb[11]));
    }
}

// ---- K1: h1 = relu(x@Ws0 + b0 + di * mean-gather(p0)); fp16 out. 8 thr/node,
// 6 active lanes own 8-col slices. Self-proj inline (fp32, bit-identical).
__global__ __launch_bounds__(128, 4) void act_k(
    const __half* __restrict__ p_in, const float* __restrict__ X,
    const float* __restrict__ ws, const float* __restrict__ bias,
    const int* __restrict__ cnt, const unsigned short* __restrict__ buckets,
    __half* __restrict__ h_out, int n_nodes, int cstride) {
    __shared__ float wlds[96 * HID];   // Ws0 fp32, 18.4 KB
    __shared__ float b_lds[HID];

    const int t = threadIdx.x;
    // zero row of h1 for next layer's gather
    if (blockIdx.x == 0 && t < 32)
        reinterpret_cast<unsigned*>(h_out + (size_t)n_nodes * RSTRIDE)[t] = 0u;

    const int j = t & 7;
    const int m = t >> 3;
    const int n = blockIdx.x * 16 + m;
    const bool nv = n < n_nodes;
    const int cn = nv ? n : 0;
    const bool active = j < 6;
    const int cb = active ? 8 * j : 0;     // col base (halfs/floats)

    // issue node-side loads before weight staging (latency hides behind it)
    const int deg_raw = cnt[(size_t)cn * cstride];
    const unsigned short* bkt = buckets + (size_t)cn * MAXDEG;
    uint4 pw[2];
#pragma unroll
    for (int b = 0; b < 2; ++b) pw[b] = reinterpret_cast<const uint4*>(bkt)[b];

    for (int i4 = t; i4 < 96 * HID / 4; i4 += 128)
        reinterpret_cast<float4*>(wlds)[i4] = reinterpret_cast<const float4*>(ws)[i4];
    if (t < HID) b_lds[t] = bias[t];
    __syncthreads();

    if (!nv) return;

    const int deg = min(deg_raw, MAXDEG);
    const float di = 1.0f / fmaxf((float)deg, 1.0f);

    // gather first: memory requests in flight ASAP
    float g[8];
    if (active) gather_w(p_in, bkt, pw, deg, cb, n_nodes, g);

    if (!active) return;

    // self-projection over own 8-col slice, full K=96
    float s[8];
#pragma unroll
    for (int c = 0; c < 8; ++c) s[c] = b_lds[cb + c];
    const float4* xr = reinterpret_cast<const float4*>(X + (size_t)cn * 96);
#pragma unroll 4
    for (int k4 = 0; k4 < 24; ++k4) {
        float4 xv = xr[k4];
#pragma unroll
        for (int c4 = 0; c4 < 4; ++c4) {
            float xk = (c4 == 0) ? xv.x : (c4 == 1) ? xv.y : (c4 == 2) ? xv.z : xv.w;
            const float4* wrk =
                reinterpret_cast<const float4*>(&wlds[(k4 * 4 + c4) * HID + cb]);
            float4 w0 = wrk[0], w1 = wrk[1];
            s[0] = fmaf(xk, w0.x, s[0]); s[1] = fmaf(xk, w0.y, s[1]);
            s[2] = fmaf(xk, w0.z, s[2]); s[3] = fmaf(xk, w0.w, s[3]);
            s[4] = fmaf(xk, w1.x, s[4]); s[5] = fmaf(xk, w1.y, s[5]);
            s[6] = fmaf(xk, w1.z, s[6]); s[7] = fmaf(xk, w1.w, s[7]);
        }
    }

    float h[8];
#pragma unroll
    for (int c = 0; c < 8; ++c) h[c] = fmaxf(fmaf(di, g[c], s[c]), 0.0f);
    uint4 o = make_uint4(pack_h2(h[0], h[1]), pack_h2(h[2], h[3]),
                         pack_h2(h[4], h[5]), pack_h2(h[6], h[7]));
    *reinterpret_cast<uint4*>(h_out + (size_t)n * RSTRIDE + cb) = o;
}

// ---- K2/K3: g = mean-gather(h_in); acc = g@Wn + h_self@Ws + b (fp16 W in LDS).
// !LAST: h_out = fp16(relu(acc)). LAST: out = relu(acc).w_pred + b_pred.
template <bool LAST>
__global__ __launch_bounds__(128, 6) void layer_k(
    const __half* __restrict__ h_in, const int* __restrict__ cnt,
    const unsigned short* __restrict__ buckets, const float* __restrict__ wn,
    const float* __restrict__ ws, const float* __restrict__ bn,
    const float* __restrict__ w_pred, const float* __restrict__ b_pred,
    __half* __restrict__ h_out, float* __restrict__ out, int n_nodes,
    int cstride) {
    __shared__ uint4 wn_s[HID * HID / 8];   // 4.6 KB, packed fp16
    __shared__ uint4 ws_s[HID * HID / 8];   // 4.6 KB
    __shared__ float bn_lds[HID];
    __shared__ float wp_lds[HID];

    const int t = threadIdx.x;
    const int j = t & 7;
    const int m = t >> 3;
    const int n = blockIdx.x * 16 + m;
    const bool nv = n < n_nodes;
    const int cn = nv ? n : 0;
    const bool active = j < 6;
    const int cb = active ? 8 * j : 0;

    if (!LAST && blockIdx.x == 0 && t < 32)
        reinterpret_cast<unsigned*>(h_out + (size_t)n_nodes * RSTRIDE)[t] = 0u;

    // issue node-side loads BEFORE weight staging
    const int deg_raw = cnt[(size_t)cn * cstride];
    const unsigned short* bkt = buckets + (size_t)cn * MAXDEG;
    uint4 pw[2];
#pragma unroll
    for (int b = 0; b < 2; ++b) pw[b] = reinterpret_cast<const uint4*>(bkt)[b];
    uint4 hv4 = *reinterpret_cast<const uint4*>(h_in + (size_t)cn * RSTRIDE + cb);

    for (int i = t; i < HID * HID / 8; i += 128) {
        const float4* wr = reinterpret_cast<const float4*>(wn) + i * 2;
        float4 a = wr[0], b = wr[1];
        wn_s[i] = make_uint4(pack_h2(a.x, a.y), pack_h2(a.z, a.w),
                             pack_h2(b.x, b.y), pack_h2(b.z, b.w));
        const float4* wr2 = reinterpret_cast<const float4*>(ws) + i * 2;
        float4 a2 = wr2[0], b2 = wr2[1];
        ws_s[i] = make_uint4(pack_h2(a2.x, a2.y), pack_h2(a2.z, a2.w),
                             pack_h2(b2.x, b2.y), pack_h2(b2.z, b2.w));
    }
    if (t < HID) bn_lds[t] = bn[t];
    if (LAST && t < HID) wp_lds[t] = w_pred[t];
    __syncthreads();

    if (!nv) return;

    const int deg = min(deg_raw, MAXDEG);
    const float di = 1.0f / fmaxf((float)deg, 1.0f);
    float g[8];
    if (active) {
        gather_w(h_in, bkt, pw, deg, cb, n_nodes, g);
#pragma unroll
        for (int c = 0; c < 8; ++c) g[c] *= di;   // mean slice
    } else {
#pragma unroll
        for (int c = 0; c < 8; ++c) g[c] = 0.0f;
    }

    // own h slice (load issued pre-staging)
    float hs[8];
    unpack_u4(hs, hv4);

    float acc[8];
#pragma unroll
    for (int c = 0; c < 8; ++c) acc[c] = active ? bn_lds[cb + c] : 0.0f;

#pragma unroll
    for (int jo = 0; jo < 6; ++jo) {
        const int srcl = (t & ~7) | jo;
#pragma unroll
        for (int r = 0; r < 8; ++r) {
            const int k = jo * 8 + r;
            float gs = __shfl(g[r], srcl, 64);
            float hv = __shfl(hs[r], srcl, 64);
            uint4 wnv = wn_s[(k * HID + cb) >> 3];
            uint4 wsv = ws_s[(k * HID + cb) >> 3];
            float wa[8], wb[8];
            unpack_u4(wa, wnv); unpack_u4(wb, wsv);
#pragma unroll
            for (int c = 0; c < 8; ++c)
                acc[c] = fmaf(gs, wa[c], fmaf(hv, wb[c], acc[c]));
        }
    }

    if (LAST) {
        float sred = 0.0f;
        if (active) {
#pragma unroll
            for (int c = 0; c < 8; ++c)
                sred = fmaf(fmaxf(acc[c], 0.0f), wp_lds[cb + c], sred);
        }
        sred += __shfl_xor(sred, 1, 64);
        sred += __shfl_xor(sred, 2, 64);
        sred += __shfl_xor(sred, 4, 64);
        if (j == 0) out[n] = sred + b_pred[0];
        return;
    }

    if (active) {
        float h[8];
#pragma unroll
        for (int c = 0; c < 8; ++c) h[c] = fmaxf(acc[c], 0.0f);
        uint4 o = make_uint4(pack_h2(h[0], h[1]), pack_h2(h[2], h[3]),
                             pack_h2(h[4], h[5]), pack_h2(h[6], h[7]));
        *reinterpret_cast<uint4*>(h_out + (size_t)n * RSTRIDE + cb) = o;
    }
}

extern "C" void kernel_launch(void* const* d_in, const int* in_sizes, int n_in,
                              void* d_out, int out_size, void* d_ws, size_t ws_size,
                              hipStream_t stream) {
    const float* x        = (const float*)d_in[0];
    const int*   ei       = (const int*)d_in[1];
    const float* w_self0  = (const float*)d_in[2];
    const float* w_neigh0 = (const float*)d_in[3];
    const float* b0       = (const float*)d_in[4];
    const float* w_self1  = (const float*)d_in[5];
    const float* w_neigh1 = (const float*)d_in[6];
    const float* b1       = (const float*)d_in[7];
    const float* w_self2  = (const float*)d_in[8];
    const float* w_neigh2 = (const float*)d_in[9];
    const float* b2       = (const float*)d_in[10];
    const float* w_pred   = (const float*)d_in[11];
    const float* b_pred   = (const float*)d_in[12];

    const int n_nodes = in_sizes[0] / 96;
    const int n_edges = in_sizes[1] / 2;
    const int* src = ei;
    const int* dst = ei + n_edges;

    // fixed-part workspace need (everything except cnt)
    const size_t need_fixed = (size_t)n_nodes * MAXDEG * 2                 // buckets
                            + 3 * ((size_t)(n_nodes + 1) * RSTRIDE * 2);   // p0,h1,h2
    // cnt stride: 4 ints (16B, 4 counters/64B line) if it fits, else 1
    int cstride = (need_fixed + (size_t)n_nodes * 4 * 4 <= ws_size) ? 4 : 1;

    // workspace layout (p0/h1/h2: padded rows + one all-zero row at n_nodes)
    char* wsb = (char*)d_ws;
    int* cnt                = (int*)wsb;              wsb += (size_t)n_nodes * cstride * 4;
    unsigned short* buckets = (unsigned short*)wsb;   wsb += (size_t)n_nodes * MAXDEG * 2;
    __half* p0 = (__half*)wsb;                        wsb += (size_t)(n_nodes + 1) * RSTRIDE * 2;
    __half* h1 = (__half*)wsb;                        wsb += (size_t)(n_nodes + 1) * RSTRIDE * 2;
    __half* h2 = (__half*)wsb;                        wsb += (size_t)(n_nodes + 1) * RSTRIDE * 2;
    float* out = (float*)d_out;

    const int gnb = (n_nodes + GNB - 1) / GNB;        // 782 proj blocks
    const int fb = (n_edges + 511) / 512;             // 1563 fill blocks (4 edges/thr)
    const int lb = (n_nodes + 15) / 16;               // 3125 layer blocks

    hipMemsetAsync(cnt, 0, (size_t)n_nodes * cstride * 4, stream);

    // K0: fill + p0(fp16)
    fill_proj_k<<<gnb + fb, 128, 0, stream>>>(x, w_neigh0, p0, n_nodes, src, dst,
                                              cnt, buckets, n_edges, gnb, cstride);
    // K1: h1 = relu(x@Ws0 + b0 + di*gather(p0))
    act_k<<<lb, 128, 0, stream>>>(p0, x, w_self0, b0, cnt, buckets, h1,
                                  n_nodes, cstride);
    // K2: layer 1 -> h2
    layer_k<false><<<lb, 128, 0, stream>>>(h1, cnt, buckets, w_neigh1, w_self1,
                                           b1, nullptr, nullptr, h2, nullptr,
                                           n_nodes, cstride);
    // K3: layer 2 + head -> out
    layer_k<true><<<lb, 128, 0, stream>>>(h2, cnt, buckets, w_neigh2, w_self2,
                                          b2, w_pred, b_pred, nullptr, out,
                                          n_nodes, cstride);
}

// Round 5
// 280.315 us; speedup vs baseline: 1.0350x; 1.0350x over previous
//
#include <hip/hip_runtime.h>
#include <hip/hip_fp16.h>

// GraphSAGE (mean agg), 3 layers + linear head, fp32 accum, fp16 transport.
// R16: hybrid of best-known pieces after R15's spill regression:
//  - K0 = R11's two-pass (p0 fp16 + s0 fp32) riding the ~46us atomic fill
//    floor (channel-throughput bound, shelved).
//  - Tables UNPADDED (96B rows, 32B-aligned -> always exactly 2 cache lines;
//    4.8MB ~fits 4MB/XCD L2). R14's padding was null for this reason.
//  - Gather: 6 lanes x uint4 (16B) per neighbor row -> 6 L2 requests/row
//    vs R13's 12 (L2 random-request-rate is the layer floor: ~9.6M req /
//    ~128 req/cy ~= 31us). Register indexing all compile-time (g[kk&7]);
//    runtime-ness confined to shfl source lane -> no scratch (R15's bug:
//    unpacked float arrays in a 48x-unrolled loop -> 125MB spill traffic).
//  - GEMM/shuffle/store paths = R13's proven fma12_h structure, untouched.

constexpr int HID = 48;
constexpr int MAXDEG = 64;
constexpr int GNB = 64;        // nodes per K0 proj block

__device__ __forceinline__ unsigned pack_h2(float a, float b) {
    __half2 h = __floats2half2_rn(a, b);
    return *reinterpret_cast<unsigned*>(&h);
}
__device__ __forceinline__ void acc_u2(float* g, uint2 u) {
    __half2 h0 = *reinterpret_cast<__half2*>(&u.x);
    __half2 h1 = *reinterpret_cast<__half2*>(&u.y);
    float2 f0 = __half22float2(h0), f1 = __half22float2(h1);
    g[0] += f0.x; g[1] += f0.y; g[2] += f1.x; g[3] += f1.y;
}
__device__ __forceinline__ void acc_u4(float* g, uint4 u) {
    acc_u2(g + 0, make_uint2(u.x, u.y));
    acc_u2(g + 4, make_uint2(u.z, u.w));
}
__device__ __forceinline__ void unpack_u2(float* v, uint2 u) {
    __half2 h0 = *reinterpret_cast<__half2*>(&u.x);
    __half2 h1 = *reinterpret_cast<__half2*>(&u.y);
    float2 f0 = __half22float2(h0), f1 = __half22float2(h1);
    v[0] = f0.x; v[1] = f0.y; v[2] = f1.x; v[3] = f1.y;
}
// acc[0..11] += s * (12 halfs at wrow)  -- proven R13 GEMM inner op
__device__ __forceinline__ void fma12_h(const uint2* __restrict__ wrow, float s,
                                        float* acc) {
    uint2 w0 = wrow[0], w1 = wrow[1], w2 = wrow[2];
    float v[12];
    unpack_u2(v + 0, w0); unpack_u2(v + 4, w1); unpack_u2(v + 8, w2);
#pragma unroll
    for (int j = 0; j < 12; ++j) acc[j] = fmaf(s, v[j], acc[j]);
}

// Wide gather: this thread accumulates cols [coff, coff+8) (halfs) of ALL
// deg neighbor rows (no parity split). Entries [0,16) prefetched in pw
// (out-of-degree -> zrow = all-zero row); [16, deg) via residual loop.
// One 16B request per row per lane; 6 active lanes cover the 96B row.
__device__ __forceinline__ void gather8(const __half* __restrict__ p,
                                        const unsigned short* __restrict__ bkt,
                                        const uint4 (&pw)[2], int deg,
                                        int coff, int zrow, float* g) {
    float ga[8], gb[8];
#pragma unroll
    for (int c = 0; c < 8; ++c) { ga[c] = 0.0f; gb[c] = 0.0f; }
#pragma unroll
    for (int b = 0; b < 2; ++b) {
        const int k0 = 8 * b;
        const unsigned w0 = pw[b].x, w1 = pw[b].y, w2 = pw[b].z, w3 = pw[b].w;
        int i0 = (k0 + 0 < deg) ? (int)(w0 & 0xffffu) : zrow;
        int i1 = (k0 + 1 < deg) ? (int)(w0 >> 16) : zrow;
        int i2 = (k0 + 2 < deg) ? (int)(w1 & 0xffffu) : zrow;
        int i3 = (k0 + 3 < deg) ? (int)(w1 >> 16) : zrow;
        int i4 = (k0 + 4 < deg) ? (int)(w2 & 0xffffu) : zrow;
        int i5 = (k0 + 5 < deg) ? (int)(w2 >> 16) : zrow;
        int i6 = (k0 + 6 < deg) ? (int)(w3 & 0xffffu) : zrow;
        int i7 = (k0 + 7 < deg) ? (int)(w3 >> 16) : zrow;
        uint4 a0 = *reinterpret_cast<const uint4*>(p + (size_t)i0 * HID + coff);
        uint4 a1 = *reinterpret_cast<const uint4*>(p + (size_t)i1 * HID + coff);
        uint4 a2 = *reinterpret_cast<const uint4*>(p + (size_t)i2 * HID + coff);
        uint4 a3 = *reinterpret_cast<const uint4*>(p + (size_t)i3 * HID + coff);
        uint4 a4 = *reinterpret_cast<const uint4*>(p + (size_t)i4 * HID + coff);
        uint4 a5 = *reinterpret_cast<const uint4*>(p + (size_t)i5 * HID + coff);
        uint4 a6 = *reinterpret_cast<const uint4*>(p + (size_t)i6 * HID + coff);
        uint4 a7 = *reinterpret_cast<const uint4*>(p + (size_t)i7 * HID + coff);
        acc_u4(ga, a0); acc_u4(gb, a1); acc_u4(ga, a2); acc_u4(gb, a3);
        acc_u4(ga, a4); acc_u4(gb, a5); acc_u4(ga, a6); acc_u4(gb, a7);
    }
    int i = 16;
    for (; i + 3 < deg; i += 4) {
        int s0 = bkt[i], s1 = bkt[i + 1], s2 = bkt[i + 2], s3 = bkt[i + 3];
        uint4 a0 = *reinterpret_cast<const uint4*>(p + (size_t)s0 * HID + coff);
        uint4 a1 = *reinterpret_cast<const uint4*>(p + (size_t)s1 * HID + coff);
        uint4 a2 = *reinterpret_cast<const uint4*>(p + (size_t)s2 * HID + coff);
        uint4 a3 = *reinterpret_cast<const uint4*>(p + (size_t)s3 * HID + coff);
        acc_u4(ga, a0); acc_u4(gb, a1); acc_u4(ga, a2); acc_u4(gb, a3);
    }
    for (; i < deg; ++i) {
        uint4 a0 = *reinterpret_cast<const uint4*>(p + (size_t)bkt[i] * HID + coff);
        acc_u4(ga, a0);
    }
#pragma unroll
    for (int c = 0; c < 8; ++c) g[c] = ga[c] + gb[c];
}

// ---- K0: blocks [0,gemm_blocks): p0 = fp16(X @ Wn), s0 = X @ Ws + b (fp32).
//      Blocks [gemm_blocks, ...): bucket fill (atomic floor ~46us). ----
__global__ __launch_bounds__(128) void fill_proj_k(
    const float* __restrict__ X, const float* __restrict__ Wn,
    const float* __restrict__ Ws, const float* __restrict__ bias,
    __half* __restrict__ p_out, float* __restrict__ s_out, int n_nodes,
    const int* __restrict__ src, const int* __restrict__ dst,
    int* __restrict__ cnt, unsigned short* __restrict__ buckets,
    int n_edges, int gemm_blocks, int cstride) {
    __shared__ float wlds[96 * HID];
    __shared__ float bias_lds[HID];
    const int t = threadIdx.x;

    if ((int)blockIdx.x >= gemm_blocks) {
        int base = (blockIdx.x - gemm_blocks) * 512 + t;
#pragma unroll
        for (int u = 0; u < 4; ++u) {
            int eidx = base + u * 128;
            if (eidx < n_edges) {
                int d = dst[eidx];
                int s = src[eidx];
                int pos = atomicAdd(&cnt[(size_t)d * cstride], 1);
                if (pos < MAXDEG) buckets[(size_t)d * MAXDEG + pos] = (unsigned short)s;
            }
        }
        return;
    }

    // zero row at index n_nodes for the gather zero-redirect trick
    if (blockIdx.x == 0 && t < 24)
        reinterpret_cast<unsigned*>(p_out + (size_t)n_nodes * HID)[t] = 0u;

    const int q = t & 3;
    const int m = t >> 2;
    const int jb = q * 12;
    const int n0 = blockIdx.x * GNB + 2 * m;
    const int n1 = n0 + 1;
    const bool v0 = n0 < n_nodes, v1 = n1 < n_nodes;
    const int cn0 = v0 ? n0 : 0, cn1 = v1 ? n1 : 0;
    const float4* xr0 = reinterpret_cast<const float4*>(X + (size_t)cn0 * 96);
    const float4* xr1 = reinterpret_cast<const float4*>(X + (size_t)cn1 * 96);

    // ---- pass A: p0 = fp16(X @ Wn) ----
    for (int i = t; i < 96 * HID; i += 128) wlds[i] = Wn[i];
    __syncthreads();
    {
        float pa[12], pb[12];
#pragma unroll
        for (int j = 0; j < 12; ++j) { pa[j] = 0.0f; pb[j] = 0.0f; }
#pragma unroll 4
        for (int k4 = 0; k4 < 24; ++k4) {
            float4 xa = xr0[k4];
            float4 xb = xr1[k4];
#pragma unroll
            for (int c = 0; c < 4; ++c) {
                float x0 = (c == 0) ? xa.x : (c == 1) ? xa.y : (c == 2) ? xa.z : xa.w;
                float x1 = (c == 0) ? xb.x : (c == 1) ? xb.y : (c == 2) ? xb.z : xb.w;
                const float4* wr =
                    reinterpret_cast<const float4*>(&wlds[(k4 * 4 + c) * HID + jb]);
#pragma unroll
                for (int j4 = 0; j4 < 3; ++j4) {
                    float4 wv = wr[j4];
                    pa[j4 * 4 + 0] = fmaf(x0, wv.x, pa[j4 * 4 + 0]);
                    pa[j4 * 4 + 1] = fmaf(x0, wv.y, pa[j4 * 4 + 1]);
                    pa[j4 * 4 + 2] = fmaf(x0, wv.z, pa[j4 * 4 + 2]);
                    pa[j4 * 4 + 3] = fmaf(x0, wv.w, pa[j4 * 4 + 3]);
                    pb[j4 * 4 + 0] = fmaf(x1, wv.x, pb[j4 * 4 + 0]);
                    pb[j4 * 4 + 1] = fmaf(x1, wv.y, pb[j4 * 4 + 1]);
                    pb[j4 * 4 + 2] = fmaf(x1, wv.z, pb[j4 * 4 + 2]);
                    pb[j4 * 4 + 3] = fmaf(x1, wv.w, pb[j4 * 4 + 3]);
                }
            }
        }
        if (v0) {
            uint2* po = reinterpret_cast<uint2*>(p_out + (size_t)n0 * HID + jb);
            po[0] = make_uint2(pack_h2(pa[0], pa[1]), pack_h2(pa[2], pa[3]));
            po[1] = make_uint2(pack_h2(pa[4], pa[5]), pack_h2(pa[6], pa[7]));
            po[2] = make_uint2(pack_h2(pa[8], pa[9]), pack_h2(pa[10], pa[11]));
        }
        if (v1) {
            uint2* po = reinterpret_cast<uint2*>(p_out + (size_t)n1 * HID + jb);
            po[0] = make_uint2(pack_h2(pb[0], pb[1]), pack_h2(pb[2], pb[3]));
            po[1] = make_uint2(pack_h2(pb[4], pb[5]), pack_h2(pb[6], pb[7]));
            po[2] = make_uint2(pack_h2(pb[8], pb[9]), pack_h2(pb[10], pb[11]));
        }
    }
    __syncthreads();

    // ---- pass B: s0 = X @ Ws + b (fp32) ----
    for (int i = t; i < 96 * HID; i += 128) wlds[i] = Ws[i];
    if (t < HID) bias_lds[t] = bias[t];
    __syncthreads();
    {
        float sa[12], sb[12];
#pragma unroll
        for (int j = 0; j < 12; ++j) {
            float b = bias_lds[jb + j];
            sa[j] = b; sb[j] = b;
        }
#pragma unroll 4
        for (int k4 = 0; k4 < 24; ++k4) {
            float4 xa = xr0[k4];
            float4 xb = xr1[k4];
#pragma unroll
            for (int c = 0; c < 4; ++c) {
                float x0 = (c == 0) ? xa.x : (c == 1) ? xa.y : (c == 2) ? xa.z : xa.w;
                float x1 = (c == 0) ? xb.x : (c == 1) ? xb.y : (c == 2) ? xb.z : xb.w;
                const float4* wr =
                    reinterpret_cast<const float4*>(&wlds[(k4 * 4 + c) * HID + jb]);
#pragma unroll
                for (int j4 = 0; j4 < 3; ++j4) {
                    float4 wv = wr[j4];
                    sa[j4 * 4 + 0] = fmaf(x0, wv.x, sa[j4 * 4 + 0]);
                    sa[j4 * 4 + 1] = fmaf(x0, wv.y, sa[j4 * 4 + 1]);
                    sa[j4 * 4 + 2] = fmaf(x0, wv.z, sa[j4 * 4 + 2]);
                    sa[j4 * 4 + 3] = fmaf(x0, wv.w, sa[j4 * 4 + 3]);
                    sb[j4 * 4 + 0] = fmaf(x1, wv.x, sb[j4 * 4 + 0]);
                    sb[j4 * 4 + 1] = fmaf(x1, wv.y, sb[j4 * 4 + 1]);
                    sb[j4 * 4 + 2] = fmaf(x1, wv.z, sb[j4 * 4 + 2]);
                    sb[j4 * 4 + 3] = fmaf(x1, wv.w, sb[j4 * 4 + 3]);
                }
            }
        }
        float4* so0 = reinterpret_cast<float4*>(s_out + (size_t)cn0 * HID + jb);
        float4* so1 = reinterpret_cast<float4*>(s_out + (size_t)cn1 * HID + jb);
#pragma unroll
        for (int j4 = 0; j4 < 3; ++j4) {
            if (v0) so0[j4] = make_float4(sa[j4 * 4 + 0], sa[j4 * 4 + 1],
                                          sa[j4 * 4 + 2], sa[j4 * 4 + 3]);
            if (v1) so1[j4] = make_float4(sb[j4 * 4 + 0], sb[j4 * 4 + 1],
                                          sb[j4 * 4 + 2], sb[j4 * 4 + 3]);
        }
    }
}

// ---- K1: h1 = relu(s0 + di * mean-gather(p0)); fp16 out. 8 thr/node,
// 6 active chunk-lanes x uint4. No LDS, no barrier. ----
__global__ __launch_bounds__(128, 6) void act_k(
    const __half* __restrict__ p_in, const float* __restrict__ s_in,
    const int* __restrict__ cnt, const unsigned short* __restrict__ buckets,
    __half* __restrict__ h_out, int n_nodes, int cstride) {
    const int t = threadIdx.x;
    // zero row of h1 for next layer's gather
    if (blockIdx.x == 0 && t < 24)
        reinterpret_cast<unsigned*>(h_out + (size_t)n_nodes * HID)[t] = 0u;

    const int cid = t & 7;
    const int m = t >> 3;
    const int n = blockIdx.x * 16 + m;
    if (n >= n_nodes) return;
    const bool active = cid < 6;
    const int cb = active ? 8 * cid : 0;

    const int deg_raw = cnt[(size_t)n * cstride];
    const unsigned short* bkt = buckets + (size_t)n * MAXDEG;
    uint4 pw[2];
#pragma unroll
    for (int b = 0; b < 2; ++b) pw[b] = reinterpret_cast<const uint4*>(bkt)[b];

    if (!active) return;

    const int deg = min(deg_raw, MAXDEG);
    const float di = 1.0f / fmaxf((float)deg, 1.0f);

    float g[8];
    gather8(p_in, bkt, pw, deg, cb, n_nodes, g);

    // own s0 slice: 8 fp32 at col cb (32B aligned)
    const float4* sr = reinterpret_cast<const float4*>(s_in + (size_t)n * HID + cb);
    float4 s0v = sr[0], s1v = sr[1];
    float h[8];
    h[0] = fmaxf(fmaf(di, g[0], s0v.x), 0.0f);
    h[1] = fmaxf(fmaf(di, g[1], s0v.y), 0.0f);
    h[2] = fmaxf(fmaf(di, g[2], s0v.z), 0.0f);
    h[3] = fmaxf(fmaf(di, g[3], s0v.w), 0.0f);
    h[4] = fmaxf(fmaf(di, g[4], s1v.x), 0.0f);
    h[5] = fmaxf(fmaf(di, g[5], s1v.y), 0.0f);
    h[6] = fmaxf(fmaf(di, g[6], s1v.z), 0.0f);
    h[7] = fmaxf(fmaf(di, g[7], s1v.w), 0.0f);
    uint4 o = make_uint4(pack_h2(h[0], h[1]), pack_h2(h[2], h[3]),
                         pack_h2(h[4], h[5]), pack_h2(h[6], h[7]));
    *reinterpret_cast<uint4*>(h_out + (size_t)n * HID + cb) = o;
}

// ---- K2/K3: g = mean-gather(h_in); acc = g@Wn + h_self@Ws + b (fp16 W LDS).
// Gather in 8-col chunk layout (6 lanes); GEMM in R13's proven (q,e) layout:
// q = t&3 owns output cols [12q,12q+12), e = (t>>2)&1 halves K; shuffles
// bridge the two layouts (g[kk&7] compile-time indexed, srcl runtime).
template <bool LAST>
__global__ __launch_bounds__(128, 6) void layer_k(
    const __half* __restrict__ h_in, const int* __restrict__ cnt,
    const unsigned short* __restrict__ buckets, const float* __restrict__ wn,
    const float* __restrict__ ws, const float* __restrict__ bn,
    const float* __restrict__ w_pred, const float* __restrict__ b_pred,
    __half* __restrict__ h_out, float* __restrict__ out, int n_nodes,
    int cstride) {
    __shared__ uint2 wn_s[HID * HID / 4];   // 4.6 KB, packed fp16
    __shared__ uint2 ws_s[HID * HID / 4];   // 4.6 KB
    __shared__ float bn_lds[HID];
    __shared__ float wp_lds[HID];

    const int t = threadIdx.x;
    const int cid = t & 7;
    const int q = t & 3;
    const int e = (t >> 2) & 1;
    const int m = t >> 3;
    const int n = blockIdx.x * 16 + m;
    const bool nv = n < n_nodes;
    const int cn = nv ? n : 0;
    const bool active = cid < 6;
    const int cb = active ? 8 * cid : 0;
    const int jb = q * 12;

    if (!LAST && blockIdx.x == 0 && t < 24)
        reinterpret_cast<unsigned*>(h_out + (size_t)n_nodes * HID)[t] = 0u;

    // issue node-side loads BEFORE weight staging (latency hides behind it)
    const int deg_raw = cnt[(size_t)cn * cstride];
    const unsigned short* bkt = buckets + (size_t)cn * MAXDEG;
    uint4 pw[2];
#pragma unroll
    for (int b = 0; b < 2; ++b) pw[b] = reinterpret_cast<const uint4*>(bkt)[b];
    uint4 hv4 = *reinterpret_cast<const uint4*>(h_in + (size_t)cn * HID + cb);

    for (int i4 = t; i4 < HID * HID / 4; i4 += 128) {
        float4 a = reinterpret_cast<const float4*>(wn)[i4];
        float4 b = reinterpret_cast<const float4*>(ws)[i4];
        wn_s[i4] = make_uint2(pack_h2(a.x, a.y), pack_h2(a.z, a.w));
        ws_s[i4] = make_uint2(pack_h2(b.x, b.y), pack_h2(b.z, b.w));
    }
    if (t < HID) bn_lds[t] = bn[t];
    if (LAST && t < HID) wp_lds[t] = w_pred[t];
    __syncthreads();

    if (!nv) return;

    const int deg = min(deg_raw, MAXDEG);
    const float di = 1.0f / fmaxf((float)deg, 1.0f);
    float g[8];
    if (active) {
        gather8(h_in, bkt, pw, deg, cb, n_nodes, g);
#pragma unroll
        for (int c = 0; c < 8; ++c) g[c] *= di;   // mean slice
    } else {
#pragma unroll
        for (int c = 0; c < 8; ++c) g[c] = 0.0f;
    }

    // own h slice in chunk layout (load issued pre-staging)
    float hs[8];
    unpack_u2(hs + 0, make_uint2(hv4.x, hv4.y));
    unpack_u2(hs + 4, make_uint2(hv4.z, hv4.w));

    float acc[12];
#pragma unroll
    for (int j = 0; j < 12; ++j) acc[j] = (e == 0) ? bn_lds[jb + j] : 0.0f;

    const int e24 = e * 24;
    const int e3 = e * 3;
#pragma unroll
    for (int kk = 0; kk < 24; ++kk) {
        const int k = e24 + kk;                       // runtime (LDS addr only)
        const int srcl = (t & ~7) | (e3 + (kk >> 3)); // lane owning col k chunk
        float gs = __shfl(g[kk & 7], srcl, 64);       // compile-time reg index
        float hv = __shfl(hs[kk & 7], srcl, 64);
        fma12_h(&wn_s[(k * HID + jb) >> 2], gs, acc);
        fma12_h(&ws_s[(k * HID + jb) >> 2], hv, acc);
    }
#pragma unroll
    for (int j = 0; j < 12; ++j) acc[j] += __shfl_xor(acc[j], 4, 64);

    if (LAST) {
        float s = 0.0f;
#pragma unroll
        for (int j = 0; j < 12; ++j) s = fmaf(fmaxf(acc[j], 0.0f), wp_lds[jb + j], s);
        s += __shfl_xor(s, 1, 64);
        s += __shfl_xor(s, 2, 64);
        if ((t & 7) == 0) out[n] = s + b_pred[0];
        return;
    }

    if (e == 0) {
        float h[12];
#pragma unroll
        for (int j = 0; j < 12; ++j) h[j] = fmaxf(acc[j], 0.0f);
        uint2* ho = reinterpret_cast<uint2*>(h_out + (size_t)n * HID + jb);
        ho[0] = make_uint2(pack_h2(h[0], h[1]), pack_h2(h[2], h[3]));
        ho[1] = make_uint2(pack_h2(h[4], h[5]), pack_h2(h[6], h[7]));
        ho[2] = make_uint2(pack_h2(h[8], h[9]), pack_h2(h[10], h[11]));
    }
}

extern "C" void kernel_launch(void* const* d_in, const int* in_sizes, int n_in,
                              void* d_out, int out_size, void* d_ws, size_t ws_size,
                              hipStream_t stream) {
    const float* x        = (const float*)d_in[0];
    const int*   ei       = (const int*)d_in[1];
    const float* w_self0  = (const float*)d_in[2];
    const float* w_neigh0 = (const float*)d_in[3];
    const float* b0       = (const float*)d_in[4];
    const float* w_self1  = (const float*)d_in[5];
    const float* w_neigh1 = (const float*)d_in[6];
    const float* b1       = (const float*)d_in[7];
    const float* w_self2  = (const float*)d_in[8];
    const float* w_neigh2 = (const float*)d_in[9];
    const float* b2       = (const float*)d_in[10];
    const float* w_pred   = (const float*)d_in[11];
    const float* b_pred   = (const float*)d_in[12];

    const int n_nodes = in_sizes[0] / 96;
    const int n_edges = in_sizes[1] / 2;
    const int* src = ei;
    const int* dst = ei + n_edges;

    // fixed-part workspace need (everything except cnt)
    const size_t need_fixed = (size_t)n_nodes * MAXDEG * 2              // buckets
                            + 3 * ((size_t)(n_nodes + 1) * HID * 2)     // p0,h1,h2
                            + (size_t)n_nodes * HID * 4;                // s0
    // cnt stride: 4 ints (16B) if it fits, else 1 (layout proven to fit R13)
    int cstride = (need_fixed + (size_t)n_nodes * 4 * 4 <= ws_size) ? 4 : 1;

    // workspace layout (p0/h1/h2 have one extra all-zero row at index n_nodes)
    char* wsb = (char*)d_ws;
    int* cnt                = (int*)wsb;              wsb += (size_t)n_nodes * cstride * 4;
    unsigned short* buckets = (unsigned short*)wsb;   wsb += (size_t)n_nodes * MAXDEG * 2;
    __half* p0 = (__half*)wsb;                        wsb += (size_t)(n_nodes + 1) * HID * 2;
    __half* h1 = (__half*)wsb;                        wsb += (size_t)(n_nodes + 1) * HID * 2;
    __half* h2 = (__half*)wsb;                        wsb += (size_t)(n_nodes + 1) * HID * 2;
    float* s0 = (float*)wsb;                          wsb += (size_t)n_nodes * HID * 4;
    float* out = (float*)d_out;

    const int gnb = (n_nodes + GNB - 1) / GNB;        // 782 proj blocks
    const int fb = (n_edges + 511) / 512;             // 1563 fill blocks (4 edges/thr)
    const int lb = (n_nodes + 15) / 16;               // 3125 layer blocks

    hipMemsetAsync(cnt, 0, (size_t)n_nodes * cstride * 4, stream);

    // K0: fill + p0(fp16) + s0(fp32)
    fill_proj_k<<<gnb + fb, 128, 0, stream>>>(x, w_neigh0, w_self0, b0, p0, s0,
                                              n_nodes, src, dst, cnt, buckets,
                                              n_edges, gnb, cstride);
    // K1: h1 = relu(s0 + di*gather(p0))
    act_k<<<lb, 128, 0, stream>>>(p0, s0, cnt, buckets, h1, n_nodes, cstride);
    // K2: layer 1 -> h2
    layer_k<false><<<lb, 128, 0, stream>>>(h1, cnt, buckets, w_neigh1, w_self1,
                                           b1, nullptr, nullptr, h2, nullptr,
                                           n_nodes, cstride);
    // K3: layer 2 + head -> out
    layer_k<true><<<lb, 128, 0, stream>>>(h2, cnt, buckets, w_neigh2, w_self2,
                                          b2, w_pred, b_pred, nullptr, out,
                                          n_nodes, cstride);
}